// Round 15
// baseline (730.072 us; speedup 1.0000x reference)
//
#include <hip/hip_runtime.h>

// ---------------------------------------------------------------------------
// Longformer (2-layer) forward, MI355X.
// R14: gemm2 switched to mfma_f32_32x32x16_bf16 (half the MFMA issues,
//      ~15% higher ceiling, bias loads 16->2/thread). C/D mapping per the
//      HW-verified m74/m101 formula. All else identical to R13.
// ---------------------------------------------------------------------------

#define Bb 2
#define Ss 4096
#define Dd 768
#define Hh 12
#define Gg 33
#define NSEPn 32
#define Ll 2
#define SPAD 4640   // S + 544 (PADL=256 left, 288 right)
#define PADL 256
#define NCLSn 5
#define NCH 16      // key chunks for global-q attention (256 keys each)
#define PARTF 1056  // floats per (bh,qt,chunk) partial: 16*64 o + 16 m + 16 l
#define PSTR 72     // Plds row stride in u16 (144B: 16B-aligned, bank-spread)

typedef unsigned short u16;
typedef __attribute__((ext_vector_type(8))) short bv8;    // 8 x bf16
typedef __attribute__((ext_vector_type(4))) short sv4;    // 4 x bf16
typedef __attribute__((ext_vector_type(4))) float f32x4;
typedef __attribute__((ext_vector_type(16))) float f32x16;

__device__ __forceinline__ float bf2f(u16 u) {
  unsigned v = ((unsigned)u) << 16;
  return __builtin_bit_cast(float, v);
}
__device__ __forceinline__ u16 f2bf(float f) {
  unsigned u = __builtin_bit_cast(unsigned, f);
  u += 0x7fffu + ((u >> 16) & 1u);
  return (u16)(u >> 16);
}
__device__ __forceinline__ void glds16(const void* g, void* l) {
  __builtin_amdgcn_global_load_lds(
      (const __attribute__((address_space(1))) void*)g,
      (__attribute__((address_space(3))) void*)l, 16, 0, 0);
}

// ---------------- setup: cnt=0, K/V pad rows = 0, bias concat ---------------
__global__ __launch_bounds__(256)
void setup_kernel(int* __restrict__ cnt, u16* __restrict__ kpk,
                  u16* __restrict__ vtpk, const float* __restrict__ bqkv,
                  const float* __restrict__ bqkvg, float* __restrict__ biasc) {
  int tid = blockIdx.x * 256 + threadIdx.x;
  if (tid < Bb) cnt[tid] = 0;
  if (tid < Ll * 3840) {
    int l = tid / 3840, c = tid - l * 3840;
    float v = (c < 2304) ? bqkv[l * 2304 + c]
                         : bqkvg[(l * 3 + 1) * Dd + (c - 2304)];
    biasc[tid] = v;
  }
  const int PADW = SPAD - Ss;                 // 544 pad rows per bh
  const int total = Bb * Hh * PADW * 64;      // 835584 elems per buffer
  for (int i = tid; i < total; i += gridDim.x * 256) {
    int bh = i / (PADW * 64);
    int rem = i - bh * (PADW * 64);
    int prow = rem >> 6, d = rem & 63;
    int row = (prow < PADL) ? prow : (Ss + prow);  // [0,PADL) U [PADL+Ss,SPAD)
    kpk[((size_t)bh * SPAD + row) * 64 + d] = 0;
    vtpk[((size_t)bh * 64 + d) * SPAD + row] = 0;
  }
}

// ---------------- sep finding --------------------------------------------
__global__ void sep_find_kernel(const int* __restrict__ ids, int* __restrict__ cnt,
                                int* __restrict__ list) {
  int i = blockIdx.x * 256 + threadIdx.x;
  if (i >= Bb * Ss) return;
  int b = i >> 12;
  if (ids[i] == 2) {
    int idx = atomicAdd(&cnt[b], 1);
    if (idx < 64) list[b * 64 + idx] = i & (Ss - 1);
  }
}

__global__ void sep_sort_kernel(const int* __restrict__ cnt, const int* __restrict__ list,
                                int* __restrict__ gpos) {
  int b = blockIdx.x;
  int t = threadIdx.x;
  int n = cnt[b]; if (n > 64) n = 64;
  if (t < Gg) gpos[b * Gg + t] = (t == 0) ? 0 : (Ss - 1);
  __syncthreads();
  if (t < n) {
    int v = list[b * 64 + t];
    int rank = 0;
    for (int j = 0; j < n; ++j) rank += (list[b * 64 + j] < v) ? 1 : 0;
    if (rank < NSEPn) gpos[b * Gg + 1 + rank] = v;
  }
}

// ------- weight fp32 (K,N) -> bf16 (N,K), batched; src slice (z/grp)*sstr+z%grp
__global__ __launch_bounds__(256)
void wconv_kernel(const float* __restrict__ src0, u16* __restrict__ dst0,
                  int K, int N, int grp, int sstr, long unit, long WLs) {
  __shared__ float t[32][33];
  int z = blockIdx.z;
  const float* src = src0 + (size_t)((z / grp) * sstr + (z % grp)) * K * N;
  u16* dst = dst0 + (size_t)(z / grp) * WLs + (size_t)(z % grp) * unit;
  int n0 = blockIdx.x * 32, k0 = blockIdx.y * 32;
  int tx = threadIdx.x & 31, ty = threadIdx.x >> 5;  // ty 0..7
  #pragma unroll
  for (int i = 0; i < 4; ++i)
    t[ty + i * 8][tx] = src[(size_t)(k0 + ty + i * 8) * N + n0 + tx];
  __syncthreads();
  #pragma unroll
  for (int i = 0; i < 4; ++i)
    dst[(size_t)(n0 + ty + i * 8) * K + k0 + tx] = f2bf(t[tx][ty + i * 8]);
}

// ---------------- embedding + LN (bf16 out only) ----------------------------
__global__ __launch_bounds__(256)
void embed_ln_kernel(const int* __restrict__ ids, const float* __restrict__ we,
                     const float* __restrict__ pe, const float* __restrict__ te,
                     const float* __restrict__ lnp, u16* __restrict__ xb) {
  int row = blockIdx.x;
  int s = row & (Ss - 1);
  int id = ids[row];
  int tid = threadIdx.x;
  float v[3]; float sm = 0.f, s2 = 0.f;
  #pragma unroll
  for (int i = 0; i < 3; ++i) {
    int c = tid + i * 256;
    float t = we[(size_t)id * Dd + c] + pe[(size_t)(s + 2) * Dd + c] + te[c];
    v[i] = t; sm += t; s2 += t * t;
  }
  __shared__ float r1[256], r2[256];
  r1[tid] = sm; r2[tid] = s2; __syncthreads();
  for (int o = 128; o; o >>= 1) {
    if (tid < o) { r1[tid] += r1[tid + o]; r2[tid] += r2[tid + o]; }
    __syncthreads();
  }
  float mean = r1[0] * (1.f / 768.f);
  float var  = r2[0] * (1.f / 768.f) - mean * mean;
  float rs = rsqrtf(var + 1e-5f);
  #pragma unroll
  for (int i = 0; i < 3; ++i) {
    int c = tid + i * 256;
    float o = (v[i] - mean) * rs * lnp[c] + lnp[Dd + c];
    xb[(size_t)row * Dd + c] = f2bf(o);
  }
}

// ------ residual (in-place bf16 carrier + 2 bf16 halves) + LN ---------------
__global__ __launch_bounds__(256)
void add_ln3_kernel(u16* __restrict__ xio, const u16* __restrict__ y0,
                    const u16* __restrict__ y1, const float* __restrict__ lnp) {
  int row = blockIdx.x;
  int tid = threadIdx.x;
  float v[3]; float sm = 0.f, s2 = 0.f;
  #pragma unroll
  for (int i = 0; i < 3; ++i) {
    int c = tid + i * 256;
    size_t idx = (size_t)row * Dd + c;
    float t = bf2f(xio[idx]) + bf2f(y0[idx]) + bf2f(y1[idx]);
    v[i] = t; sm += t; s2 += t * t;
  }
  __shared__ float r1[256], r2[256];
  r1[tid] = sm; r2[tid] = s2; __syncthreads();
  for (int o = 128; o; o >>= 1) {
    if (tid < o) { r1[tid] += r1[tid + o]; r2[tid] += r2[tid + o]; }
    __syncthreads();
  }
  float mean = r1[0] * (1.f / 768.f);
  float var  = r2[0] * (1.f / 768.f) - mean * mean;
  float rs = rsqrtf(var + 1e-5f);
  #pragma unroll
  for (int i = 0; i < 3; ++i) {
    int c = tid + i * 256;
    float o = (v[i] - mean) * rs * lnp[c] + lnp[Dd + c];
    xio[(size_t)row * Dd + c] = f2bf(o);
  }
}

// ------- GEMM2: 128x128 2-buffer, 32x32x16 MFMA, T2 swizzle, T1 XCD swizzle -
// C/D mapping (m74/m101): col=lane&31, row=(reg&3)+8*(reg>>2)+4*(lane>>5).
// MODE 0: split-K: z==0 -> bf16 o0 (+bias); z==1 -> bf16 o1 (no bias)
// MODE 1: bf16 [M][N], exact gelu
// MODE 2: fused QKV+gKV: N=3840; secs: q pk / k pad / v^T pad / gk pk / gv^T
// MODE 4: bf16 [M][N] * scale
template <int MODE, bool XSWZ>
__global__ __launch_bounds__(256)
void gemm2_kernel(const u16* __restrict__ A, const u16* __restrict__ Bt,
                  const float* __restrict__ bias,
                  u16* __restrict__ o0, u16* __restrict__ o1, u16* __restrict__ o2,
                  u16* __restrict__ o3, u16* __restrict__ o4,
                  int N, int Ks, int Kl, float scale) {
  __shared__ u16 la[2][128 * 32], lb[2][128 * 32];
  int tid = threadIdx.x;
  int wave = tid >> 6, lane = tid & 63;
  int wr = wave >> 1, wc = wave & 1;
  int l31 = lane & 31, khi = lane >> 5;
  // T1: XCD-aware bijective remap of the x-y plane (requires NB % 8 == 0)
  int bx = blockIdx.x, by = blockIdx.y;
  if (XSWZ) {
    int gx = gridDim.x;
    int nlin = bx + gx * by;
    int NB = gx * gridDim.y;
    nlin = (nlin & 7) * (NB >> 3) + (nlin >> 3);
    bx = nlin % gx;
    by = nlin / gx;
  }
  int row0 = by * 128, col0 = bx * 128;
  int koff = blockIdx.z * Kl;

  // T2 swizzle: linear LDS dest; lane fetches logical granule (l&3)^((l>>3)&3)
  int sgr = (lane & 3) ^ ((lane >> 3) & 3);
  const u16* Ag = A + (size_t)(row0 + wave * 32 + (lane >> 2)) * Ks + sgr * 8 + koff;
  const u16* Bg = Bt + (size_t)(col0 + wave * 32 + (lane >> 2)) * Ks + sgr * 8 + koff;
  int wofs = wave * 1024;
  int rsw = (l31 >> 1) & 3;                // row-derived swizzle term

  f32x16 acc[2][2];
  #pragma unroll
  for (int i = 0; i < 2; ++i)
    #pragma unroll
    for (int j = 0; j < 2; ++j)
      #pragma unroll
      for (int e = 0; e < 16; ++e) acc[i][j][e] = 0.f;

  glds16(Ag, la[0] + wofs);
  glds16(Ag + (size_t)16 * Ks, la[0] + wofs + 512);
  glds16(Bg, lb[0] + wofs);
  glds16(Bg + (size_t)16 * Ks, lb[0] + wofs + 512);
  __syncthreads();

  int nk = Kl >> 5;
  for (int t = 0; t < nk; ++t) {
    int cur = t & 1;
    if (t + 1 < nk) {
      int k1 = (t + 1) << 5;
      glds16(Ag + k1, la[cur ^ 1] + wofs);
      glds16(Ag + (size_t)16 * Ks + k1, la[cur ^ 1] + wofs + 512);
      glds16(Bg + k1, lb[cur ^ 1] + wofs);
      glds16(Bg + (size_t)16 * Ks + k1, lb[cur ^ 1] + wofs + 512);
    }
    bv8 af[2][2], bf_[2][2];
    #pragma unroll
    for (int i = 0; i < 2; ++i) {
      int row = wr * 64 + i * 32 + l31;
      af[i][0] = *reinterpret_cast<const bv8*>(la[cur] + row * 32 + ((khi ^ rsw) << 3));
      af[i][1] = *reinterpret_cast<const bv8*>(la[cur] + row * 32 + (((2 + khi) ^ rsw) << 3));
    }
    #pragma unroll
    for (int j = 0; j < 2; ++j) {
      int row = wc * 64 + j * 32 + l31;
      bf_[j][0] = *reinterpret_cast<const bv8*>(lb[cur] + row * 32 + ((khi ^ rsw) << 3));
      bf_[j][1] = *reinterpret_cast<const bv8*>(lb[cur] + row * 32 + (((2 + khi) ^ rsw) << 3));
    }
    __builtin_amdgcn_s_setprio(1);
    #pragma unroll
    for (int h = 0; h < 2; ++h)
      #pragma unroll
      for (int i = 0; i < 2; ++i)
        #pragma unroll
        for (int j = 0; j < 2; ++j)
          acc[i][j] = __builtin_amdgcn_mfma_f32_32x32x16_bf16(af[i][h], bf_[j][h], acc[i][j], 0, 0, 0);
    __builtin_amdgcn_s_setprio(0);
    __syncthreads();
  }

  #pragma unroll
  for (int i = 0; i < 2; ++i) {
    int growb = row0 + wr * 64 + i * 32 + 4 * khi;  // + 8*q + p
    #pragma unroll
    for (int j = 0; j < 2; ++j) {
      int gcol = col0 + wc * 64 + j * 32 + l31;
      float bvl = bias[gcol];
      if (MODE == 0) {
        u16* od = blockIdx.z ? o1 : o0;
        float badd = blockIdx.z ? 0.f : bvl;
        #pragma unroll
        for (int q = 0; q < 4; ++q)
          #pragma unroll
          for (int p = 0; p < 4; ++p)
            od[(size_t)(growb + 8 * q + p) * N + gcol] = f2bf(acc[i][j][4 * q + p] + badd);
      } else if (MODE == 1) {
        #pragma unroll
        for (int q = 0; q < 4; ++q)
          #pragma unroll
          for (int p = 0; p < 4; ++p) {
            float v = acc[i][j][4 * q + p] + bvl;
            v = 0.5f * v * (1.0f + erff(v * 0.70710678118654752f));
            o0[(size_t)(growb + 8 * q + p) * N + gcol] = f2bf(v);
          }
      } else if (MODE == 4) {
        #pragma unroll
        for (int q = 0; q < 4; ++q)
          #pragma unroll
          for (int p = 0; p < 4; ++p)
            o0[(size_t)(growb + 8 * q + p) * N + gcol] = f2bf((acc[i][j][4 * q + p] + bvl) * scale);
      } else if (MODE == 2) {
        int sec = (col0 >> 7) / 6;        // 0..4, block-uniform
        int colr = gcol - sec * 768;
        int hh = colr >> 6, d = colr & 63;
        int bb = growb >> 12;
        size_t bhh = (size_t)(bb * Hh + hh);
        if (sec == 0) {
          #pragma unroll
          for (int q = 0; q < 4; ++q) {
            int s = (growb + 8 * q) & (Ss - 1);
            #pragma unroll
            for (int p = 0; p < 4; ++p)
              o0[(bhh * Ss + s + p) * 64 + d] = f2bf((acc[i][j][4 * q + p] + bvl) * scale);
          }
        } else if (sec == 1) {
          #pragma unroll
          for (int q = 0; q < 4; ++q) {
            int s = (growb + 8 * q) & (Ss - 1);
            #pragma unroll
            for (int p = 0; p < 4; ++p)
              o1[(bhh * SPAD + PADL + s + p) * 64 + d] = f2bf(acc[i][j][4 * q + p] + bvl);
          }
        } else if (sec == 2) {
          #pragma unroll
          for (int q = 0; q < 4; ++q) {
            int s = (growb + 8 * q) & (Ss - 1);
            sv4 pk;
            #pragma unroll
            for (int p = 0; p < 4; ++p) pk[p] = (short)f2bf(acc[i][j][4 * q + p] + bvl);
            *reinterpret_cast<sv4*>(o2 + (bhh * 64 + d) * SPAD + PADL + s) = pk;
          }
        } else if (sec == 3) {
          #pragma unroll
          for (int q = 0; q < 4; ++q) {
            int s = (growb + 8 * q) & (Ss - 1);
            #pragma unroll
            for (int p = 0; p < 4; ++p)
              o3[(bhh * Ss + s + p) * 64 + d] = f2bf(acc[i][j][4 * q + p] + bvl);
          }
        } else {
          #pragma unroll
          for (int q = 0; q < 4; ++q) {
            int s = (growb + 8 * q) & (Ss - 1);
            sv4 pk;
            #pragma unroll
            for (int p = 0; p < 4; ++p) pk[p] = (short)f2bf(acc[i][j][4 * q + p] + bvl);
            *reinterpret_cast<sv4*>(o4 + (bhh * 64 + d) * Ss + s) = pk;
          }
        }
      }
    }
  }
}

// ---------------- gathers (merged: glob K/V + xg) ---------------------------
__global__ __launch_bounds__(256)
void gather_kernel(const u16* __restrict__ kpk, const u16* __restrict__ vtpk,
                   const u16* __restrict__ xb, const int* __restrict__ gpos,
                   u16* __restrict__ kg, u16* __restrict__ vgt,
                   u16* __restrict__ xg) {
  int blk = blockIdx.x;
  int tid = threadIdx.x;
  if (blk < Bb * Hh) {
    int bh = blk;
    int b = bh / Hh;
    for (int idx = tid; idx < 64 * 64; idx += 256) {
      int g = idx >> 6, d = idx & 63;
      u16 kv = 0, vv = 0;
      if (g < Gg) {
        int p = gpos[b * Gg + g];
        kv = kpk[((size_t)bh * SPAD + PADL + p) * 64 + d];
        vv = vtpk[((size_t)bh * 64 + d) * SPAD + PADL + p];
      }
      kg[(size_t)bh * 4096 + idx] = kv;
      vgt[((size_t)bh * 64 + d) * 64 + g] = vv;
    }
  } else {
    int rg = blk - Bb * Hh;   // b*G+g
    int b = rg / Gg;
    int p = gpos[rg];
    for (int c = tid; c < Dd; c += 256)
      xg[(size_t)rg * Dd + c] = xb[((size_t)b * Ss + p) * Dd + c];
  }
}

// ---------------- local (sliding window + global-key) attention -------------
#define LOCAL_NB (Bb * Hh * (Ss / 64))   // 1536 blocks, %8 == 0
__global__ __launch_bounds__(128)
void attn_local_kernel(const u16* __restrict__ qpk, const u16* __restrict__ kpk,
                       const u16* __restrict__ vtpk, const u16* __restrict__ kg,
                       const u16* __restrict__ vgt, const int* __restrict__ amask,
                       u16* __restrict__ ctx) {
  __shared__ u16 Plds[4][16 * PSTR];
  int bid = blockIdx.x;
  int swz = (bid & 7) * (LOCAL_NB / 8) + (bid >> 3);
  int qb = swz & 63;
  int bh = swz >> 6;
  int b = bh / Hh;
  int h = bh - b * Hh;
  int wv = threadIdx.x >> 6;       // 0..1
  int q0 = qb * 64;                // block window base
  int qA = q0 + wv * 32;           // tile A rows qA..qA+15; tile B +16
  int lane = threadIdx.x & 63;
  int lg = lane >> 4, lc = lane & 15;
  int lg4 = lg * 4;
  int qa = qA + lc, qbq = qA + 16 + lc;   // this lane's queries (A, B)

  const u16* qrowA = qpk + ((size_t)bh * Ss + qA + lc) * 64;
  bv8 aqA0 = *reinterpret_cast<const bv8*>(qrowA + lg * 8);
  bv8 aqA1 = *reinterpret_cast<const bv8*>(qrowA + 32 + lg * 8);
  const u16* qrowB = qrowA + 16 * 64;
  bv8 aqB0 = *reinterpret_cast<const bv8*>(qrowB + lg * 8);
  bv8 aqB1 = *reinterpret_cast<const bv8*>(qrowB + 32 + lg * 8);

  f32x4 oA[4], oB[4];
  #pragma unroll
  for (int i = 0; i < 4; ++i) { oA[i] = (f32x4){0.f,0.f,0.f,0.f}; oB[i] = (f32x4){0.f,0.f,0.f,0.f}; }
  float mrunA = -1e30f, lrunA = 0.f, mrunB = -1e30f, lrunB = 0.f;

  const u16* kgb = kg + ((size_t)bh) * 64 * 64;
  const u16* vgb = vgt + ((size_t)bh) * 64 * 64;
  const u16* kb = kpk + ((size_t)bh) * SPAD * 64;
  const u16* vb = vtpk + ((size_t)bh) * 64 * SPAD;
  const int* amb = amask + b * Ss;
  u16* PA = &Plds[wv * 2][0];
  u16* PB = &Plds[wv * 2 + 1][0];

  // preload K frags for step 0 (global keys)
  bv8 kc[8];
  #pragma unroll
  for (int j = 0; j < 4; ++j) {
    const u16* kr = kgb + (size_t)(j * 16 + lc) * 64;
    kc[2 * j]     = *reinterpret_cast<const bv8*>(kr + lg * 8);
    kc[2 * j + 1] = *reinterpret_cast<const bv8*>(kr + 32 + lg * 8);
  }
  // prefetch amask word for step 1
  int amvN;
  { int ni = min(max(q0 - 256 + lane, 0), Ss - 1); amvN = amb[ni]; }

  for (int step = 0; step < 10; ++step) {
    bool isg = (step == 0);
    int ks = isg ? 0 : (q0 - 256 + (step - 1) * 64);
    int amvC = amvN;
    if (step < 9) { int ni = min(max(q0 - 256 + step * 64 + lane, 0), Ss - 1); amvN = amb[ni]; }

    // V loads (shared by both tiles)
    bv8 vf0[4], vf1[4];
    #pragma unroll
    for (int nt = 0; nt < 4; ++nt) {
      const u16* vr = isg ? (vgb + (size_t)(nt * 16 + lc) * 64)
                          : (vb + (size_t)(nt * 16 + lc) * SPAD + PADL + ks);
      vf0[nt] = *reinterpret_cast<const bv8*>(vr + lg * 8);
      vf1[nt] = *reinterpret_cast<const bv8*>(vr + 32 + lg * 8);
    }
    // key-validity mask
    unsigned long long kmask;
    if (isg) {
      kmask = (1ull << Gg) - 1;
    } else {
      int kidx = ks + lane;
      kmask = __ballot((kidx >= 0) && (kidx < Ss) && (amvC > 0));
    }
    // QK^T swapped: scX[j] = scores for keys ks+j*16+lg4..+3, query (tile, lc)
    f32x4 scA[4], scB[4];
    __builtin_amdgcn_s_setprio(1);
    #pragma unroll
    for (int j = 0; j < 4; ++j) {
      f32x4 z = (f32x4){0.f, 0.f, 0.f, 0.f};
      scA[j] = __builtin_amdgcn_mfma_f32_16x16x32_bf16(kc[2 * j], aqA0, z, 0, 0, 0);
      scA[j] = __builtin_amdgcn_mfma_f32_16x16x32_bf16(kc[2 * j + 1], aqA1, scA[j], 0, 0, 0);
      scB[j] = __builtin_amdgcn_mfma_f32_16x16x32_bf16(kc[2 * j], aqB0, z, 0, 0, 0);
      scB[j] = __builtin_amdgcn_mfma_f32_16x16x32_bf16(kc[2 * j + 1], aqB1, scB[j], 0, 0, 0);
    }
    __builtin_amdgcn_s_setprio(0);
    // reload kc IN PLACE for next step (WAR; hides under softmax+PV)
    if (step < 9) {
      int ksn = q0 - 256 + step * 64;
      #pragma unroll
      for (int j = 0; j < 4; ++j) {
        const u16* kr = kb + (size_t)(PADL + ksn + j * 16 + lc) * 64;
        kc[2 * j]     = *reinterpret_cast<const bv8*>(kr + lg * 8);
        kc[2 * j + 1] = *reinterpret_cast<const bv8*>(kr + 32 + lg * 8);
      }
    }
    // masking: steps 2..8 with full kmask are band-safe for all 64 queries
    bool fast = (!isg) && (step >= 2) && (step <= 8) && (kmask == ~0ull);
    float mlocA = -1e30f, mlocB = -1e30f;
    if (fast) {
      #pragma unroll
      for (int j = 0; j < 4; ++j)
        #pragma unroll
        for (int r = 0; r < 4; ++r) {
          mlocA = fmaxf(mlocA, scA[j][r]);
          mlocB = fmaxf(mlocB, scB[j][r]);
        }
    } else {
      #pragma unroll
      for (int j = 0; j < 4; ++j)
        #pragma unroll
        for (int r = 0; r < 4; ++r) {
          int kk = ks + j * 16 + lg4 + r;
          bool okk = (kmask >> (j * 16 + lg4 + r)) & 1;
          bool okA = okk, okB = okk;
          if (!isg) {
            okA = okA && ((unsigned)(kk - qa + 256) <= 512u);
            okB = okB && ((unsigned)(kk - qbq + 256) <= 512u);
          }
          scA[j][r] = okA ? scA[j][r] : -1e9f;
          scB[j][r] = okB ? scB[j][r] : -1e9f;
          mlocA = fmaxf(mlocA, scA[j][r]);
          mlocB = fmaxf(mlocB, scB[j][r]);
        }
    }
    mlocA = fmaxf(mlocA, __shfl_xor(mlocA, 16));
    mlocA = fmaxf(mlocA, __shfl_xor(mlocA, 32));
    mlocB = fmaxf(mlocB, __shfl_xor(mlocB, 16));
    mlocB = fmaxf(mlocB, __shfl_xor(mlocB, 32));
    // defer-max: only rescale when max grows by > 8 for some query
    if (__any(mlocA > mrunA + 8.f)) {
      float nm = fmaxf(mrunA, mlocA);
      float scal = __expf(mrunA - nm);
      mrunA = nm;
      lrunA *= scal;
      #pragma unroll
      for (int r = 0; r < 4; ++r) {
        float sr = __shfl(scal, lg4 + r);
        #pragma unroll
        for (int nt = 0; nt < 4; ++nt) oA[nt][r] *= sr;
      }
    }
    if (__any(mlocB > mrunB + 8.f)) {
      float nm = fmaxf(mrunB, mlocB);
      float scal = __expf(mrunB - nm);
      mrunB = nm;
      lrunB *= scal;
      #pragma unroll
      for (int r = 0; r < 4; ++r) {
        float sr = __shfl(scal, lg4 + r);
        #pragma unroll
        for (int nt = 0; nt < 4; ++nt) oB[nt][r] *= sr;
      }
    }
    float psumA = 0.f, psumB = 0.f;
    #pragma unroll
    for (int j = 0; j < 4; ++j) {
      sv4 pkA, pkB;
      #pragma unroll
      for (int r = 0; r < 4; ++r) {
        float pA = __expf(scA[j][r] - mrunA);
        float pB = __expf(scB[j][r] - mrunB);
        psumA += pA; psumB += pB;
        pkA[r] = (short)f2bf(pA);
        pkB[r] = (short)f2bf(pB);
      }
      *reinterpret_cast<sv4*>(PA + lc * PSTR + j * 16 + lg4) = pkA;
      *reinterpret_cast<sv4*>(PB + lc * PSTR + j * 16 + lg4) = pkB;
    }
    psumA += __shfl_xor(psumA, 16);
    psumA += __shfl_xor(psumA, 32);
    psumB += __shfl_xor(psumB, 16);
    psumB += __shfl_xor(psumB, 32);
    lrunA += psumA;
    lrunB += psumB;
    // PV (V frags shared between tiles)
    __builtin_amdgcn_s_setprio(1);
    {
      bv8 apA = *reinterpret_cast<const bv8*>(PA + lc * PSTR + lg * 8);
      bv8 apB = *reinterpret_cast<const bv8*>(PB + lc * PSTR + lg * 8);
      #pragma unroll
      for (int nt = 0; nt < 4; ++nt) {
        oA[nt] = __builtin_amdgcn_mfma_f32_16x16x32_bf16(apA, vf0[nt], oA[nt], 0, 0, 0);
        oB[nt] = __builtin_amdgcn_mfma_f32_16x16x32_bf16(apB, vf0[nt], oB[nt], 0, 0, 0);
      }
      apA = *reinterpret_cast<const bv8*>(PA + lc * PSTR + 32 + lg * 8);
      apB = *reinterpret_cast<const bv8*>(PB + lc * PSTR + 32 + lg * 8);
      #pragma unroll
      for (int nt = 0; nt < 4; ++nt) {
        oA[nt] = __builtin_amdgcn_mfma_f32_16x16x32_bf16(apA, vf1[nt], oA[nt], 0, 0, 0);
        oB[nt] = __builtin_amdgcn_mfma_f32_16x16x32_bf16(apB, vf1[nt], oB[nt], 0, 0, 0);
      }
    }
    __builtin_amdgcn_s_setprio(0);
  }
  float invA = 1.0f / lrunA, invB = 1.0f / lrunB;
  #pragma unroll
  for (int r = 0; r < 4; ++r) {
    float invrA = __shfl(invA, lg4 + r);
    float invrB = __shfl(invB, lg4 + r);
    size_t rowA = ((size_t)b * Ss + qA + lg4 + r) * Dd + h * 64;
    size_t rowB = rowA + (size_t)16 * Dd;
    #pragma unroll
    for (int nt = 0; nt < 4; ++nt) {
      ctx[rowA + nt * 16 + lc] = f2bf(oA[nt][r] * invrA);
      ctx[rowB + nt * 16 + lc] = f2bf(oB[nt][r] * invrB);
    }
  }
}

// ---------------- global-query attention: lane-local flash MFMA -------------
__global__ __launch_bounds__(192)
void attn_globalq_kernel(const u16* __restrict__ qgb, const u16* __restrict__ kgf,
                         const u16* __restrict__ vgt, const int* __restrict__ amask,
                         float* __restrict__ part) {
  __shared__ u16 Plds[3][16 * PSTR];
  int blk = blockIdx.x;
  int ch = blk & (NCH - 1);
  int bh = blk / NCH;
  int b = bh / Hh, h = bh - b * Hh;
  int wv = threadIdx.x >> 6;  // q-tile 0..2
  int lane = threadIdx.x & 63;
  int lg = lane >> 4, lc = lane & 15;
  int lg4 = lg * 4;

  int qrow = wv * 16 + lc;
  bv8 aq0 = (bv8)0, aq1 = (bv8)0;
  if (qrow < Gg) {
    const u16* qr = qgb + (size_t)(b * Gg + qrow) * Dd + h * 64;
    aq0 = *reinterpret_cast<const bv8*>(qr + lg * 8);
    aq1 = *reinterpret_cast<const bv8*>(qr + 32 + lg * 8);
  }

  f32x4 o[4];
  #pragma unroll
  for (int i = 0; i < 4; ++i) o[i] = (f32x4){0.f, 0.f, 0.f, 0.f};
  float mrun = -1e30f, lrun = 0.f;

  const u16* kb = kgf + ((size_t)bh) * Ss * 64;
  const u16* vb = vgt + ((size_t)bh) * 64 * Ss;
  const int* amb = amask + b * Ss;
  int ks0 = ch * (Ss / NCH);
  u16* P = &Plds[wv][0];

  // preload K frags for step 0
  bv8 kc[8];
  #pragma unroll
  for (int j = 0; j < 4; ++j) {
    const u16* kr = kb + (size_t)(ks0 + j * 16 + lc) * 64;
    kc[2 * j]     = *reinterpret_cast<const bv8*>(kr + lg * 8);
    kc[2 * j + 1] = *reinterpret_cast<const bv8*>(kr + 32 + lg * 8);
  }

  for (int st = 0; st < 4; ++st) {
    int ks = ks0 + st * 64;
    // V loads
    bv8 vf0[4], vf1[4];
    #pragma unroll
    for (int nt = 0; nt < 4; ++nt) {
      const u16* vr = vb + (size_t)(nt * 16 + lc) * Ss + ks;
      vf0[nt] = *reinterpret_cast<const bv8*>(vr + lg * 8);
      vf1[nt] = *reinterpret_cast<const bv8*>(vr + 32 + lg * 8);
    }
    unsigned long long kmask = __ballot(amb[ks + lane] > 0);
    // QK^T swapped
    f32x4 sc[4];
    __builtin_amdgcn_s_setprio(1);
    #pragma unroll
    for (int j = 0; j < 4; ++j) {
      f32x4 z = (f32x4){0.f, 0.f, 0.f, 0.f};
      sc[j] = __builtin_amdgcn_mfma_f32_16x16x32_bf16(kc[2 * j], aq0, z, 0, 0, 0);
      sc[j] = __builtin_amdgcn_mfma_f32_16x16x32_bf16(kc[2 * j + 1], aq1, sc[j], 0, 0, 0);
    }
    __builtin_amdgcn_s_setprio(0);
    // reload kc for next step
    if (st < 3) {
      int ksn = ks0 + (st + 1) * 64;
      #pragma unroll
      for (int j = 0; j < 4; ++j) {
        const u16* kr = kb + (size_t)(ksn + j * 16 + lc) * 64;
        kc[2 * j]     = *reinterpret_cast<const bv8*>(kr + lg * 8);
        kc[2 * j + 1] = *reinterpret_cast<const bv8*>(kr + 32 + lg * 8);
      }
    }
    float mloc = -1e30f;
    if (kmask == ~0ull) {
      #pragma unroll
      for (int j = 0; j < 4; ++j)
        #pragma unroll
        for (int r = 0; r < 4; ++r) mloc = fmaxf(mloc, sc[j][r]);
    } else {
      #pragma unroll
      for (int j = 0; j < 4; ++j)
        #pragma unroll
        for (int r = 0; r < 4; ++r) {
          bool ok = (kmask >> (j * 16 + lg4 + r)) & 1;
          sc[j][r] = ok ? sc[j][r] : -1e9f;
          mloc = fmaxf(mloc, sc[j][r]);
        }
    }
    mloc = fmaxf(mloc, __shfl_xor(mloc, 16));
    mloc = fmaxf(mloc, __shfl_xor(mloc, 32));
    if (__any(mloc > mrun + 8.f)) {
      float nm = fmaxf(mrun, mloc);
      float scal = __expf(mrun - nm);
      mrun = nm;
      lrun *= scal;
      #pragma unroll
      for (int r = 0; r < 4; ++r) {
        float sr = __shfl(scal, lg4 + r);
        #pragma unroll
        for (int nt = 0; nt < 4; ++nt) o[nt][r] *= sr;
      }
    }
    float psum = 0.f;
    #pragma unroll
    for (int j = 0; j < 4; ++j) {
      sv4 pk;
      #pragma unroll
      for (int r = 0; r < 4; ++r) {
        float p = __expf(sc[j][r] - mrun);
        psum += p;
        pk[r] = (short)f2bf(p);
      }
      *reinterpret_cast<sv4*>(P + lc * PSTR + j * 16 + lg4) = pk;
    }
    psum += __shfl_xor(psum, 16);
    psum += __shfl_xor(psum, 32);
    lrun += psum;
    __builtin_amdgcn_s_setprio(1);
    {
      bv8 ap = *reinterpret_cast<const bv8*>(P + lc * PSTR + lg * 8);
      #pragma unroll
      for (int nt = 0; nt < 4; ++nt)
        o[nt] = __builtin_amdgcn_mfma_f32_16x16x32_bf16(ap, vf0[nt], o[nt], 0, 0, 0);
      ap = *reinterpret_cast<const bv8*>(P + lc * PSTR + 32 + lg * 8);
      #pragma unroll
      for (int nt = 0; nt < 4; ++nt)
        o[nt] = __builtin_amdgcn_mfma_f32_16x16x32_bf16(ap, vf1[nt], o[nt], 0, 0, 0);
    }
    __builtin_amdgcn_s_setprio(0);
  }

  float* pb = part + ((size_t)(bh * 3 + wv) * NCH + ch) * PARTF;
  #pragma unroll
  for (int r = 0; r < 4; ++r) {
    int row = lg4 + r;
    #pragma unroll
    for (int nt = 0; nt < 4; ++nt)
      pb[row * 64 + nt * 16 + lc] = o[nt][r];
  }
  if (lg == 0) {
    pb[1024 + lc] = mrun;
    pb[1040 + lc] = lrun;
  }
}

// merge NCH chunk-partials and scatter into ctx rows at gpos
__global__ __launch_bounds__(256)
void attn_gmerge_kernel(const float* __restrict__ part, const int* __restrict__ gpos,
                        u16* __restrict__ ctx) {
  __shared__ float wgt[Gg][NCH];
  __shared__ float sinvl[Gg];
  int bh = blockIdx.x;
  int b = bh / Hh, h = bh - b * Hh;
  int tid = threadIdx.x;
  if (tid < Gg) {
    int qt = tid >> 4, rr = tid & 15;
    const float* pb = part + ((size_t)(bh * 3 + qt) * NCH) * PARTF;
    float mx = -1e30f;
    for (int c = 0; c < NCH; ++c) mx = fmaxf(mx, pb[c * PARTF + 1024 + rr]);
    float l = 0.f;
    for (int c = 0; c < NCH; ++c) {
      float w = __expf(pb[c * PARTF + 1024 + rr] - mx);
      wgt[tid][c] = w;
      l += w * pb[c * PARTF + 1040 + rr];
    }
    sinvl[tid] = 1.0f / l;
  }
  __syncthreads();
  for (int e = tid; e < Gg * 64; e += 256) {
    int row = e >> 6, d = e & 63;
    int qt = row >> 4, rr = row & 15;
    const float* pb = part + ((size_t)(bh * 3 + qt) * NCH) * PARTF + rr * 64 + d;
    float acc = 0.f;
    #pragma unroll
    for (int c = 0; c < NCH; ++c) acc += wgt[row][c] * pb[c * PARTF];
    int pos = gpos[b * Gg + row];
    ctx[((size_t)b * Ss + pos) * Dd + h * 64 + d] = f2bf(acc * sinvl[row]);
  }
}

// ---------------- classifier (bf16 x) ---------------------------------------
__global__ __launch_bounds__(64)
void cls_kernel(const u16* __restrict__ x, const float* __restrict__ W,
                const float* __restrict__ bias, const int* __restrict__ gpos,
                float* __restrict__ out) {
  int r = blockIdx.x;  // b*32 + i
  int b = r >> 5, i = r & 31;
  int pos = gpos[b * Gg + 1 + i];
  int lane = threadIdx.x;
  const u16* xr = x + ((size_t)b * Ss + pos) * Dd;
  float acc[NCLSn] = {0.f, 0.f, 0.f, 0.f, 0.f};
  for (int k = lane; k < Dd; k += 64) {
    float xv = bf2f(xr[k]);
    #pragma unroll
    for (int c = 0; c < NCLSn; ++c) acc[c] += xv * W[c * Dd + k];
  }
  #pragma unroll
  for (int c = 0; c < NCLSn; ++c) {
    #pragma unroll
    for (int off = 1; off < 64; off <<= 1) acc[c] += __shfl_xor(acc[c], off);
  }
  if (lane == 0) {
    #pragma unroll
    for (int c = 0; c < NCLSn; ++c) out[r * NCLSn + c] = acc[c] + bias[c];
  }
}

// ---------------------------------------------------------------------------
extern "C" void kernel_launch(void* const* d_in, const int* in_sizes, int n_in,
                              void* d_out, int out_size, void* d_ws, size_t ws_size,
                              hipStream_t stream) {
  const int* ids     = (const int*)d_in[0];
  const int* amask   = (const int*)d_in[1];
  const float* we    = (const float*)d_in[2];
  const float* pe    = (const float*)d_in[3];
  const float* te    = (const float*)d_in[4];
  const float* embln = (const float*)d_in[5];
  const float* Wqkv  = (const float*)d_in[6];
  const float* bqkv  = (const float*)d_in[7];
  const float* Wqkvg = (const float*)d_in[8];
  const float* bqkvg = (const float*)d_in[9];
  const float* Wo    = (const float*)d_in[10];
  const float* bo    = (const float*)d_in[11];
  const float* ln1   = (const float*)d_in[12];
  const float* Wff1  = (const float*)d_in[13];
  const float* bff1  = (const float*)d_in[14];
  const float* Wff2  = (const float*)d_in[15];
  const float* bff2  = (const float*)d_in[16];
  const float* ln2   = (const float*)d_in[17];
  const float* clsW  = (const float*)d_in[18];
  const float* clsb  = (const float*)d_in[19];
  float* out = (float*)d_out;

  char* ws = (char*)d_ws;
  size_t off = 0;
  auto alloc = [&](size_t bytes) { size_t o = off; off += (bytes + 255) & ~(size_t)255; return o; };

  const size_t DD = (size_t)Dd * Dd;        // 589824
  const size_t DF = (size_t)Dd * 4 * Dd;    // 2359296
  const size_t WL = 7 * DD + 2 * DF;        // elems per layer
  // Wb layout per layer: [q,k,v, gk,gv, gq, wo, ff1, ff2]

  size_t o_cnt  = alloc(Bb * 4);
  size_t o_list = alloc(Bb * 64 * 4);
  size_t o_gpos = alloc(Bb * Gg * 4);
  size_t o_bias = alloc((size_t)Ll * 3840 * 4);
  size_t o_w    = alloc(WL * Ll * 2);
  size_t o_xb   = alloc((size_t)Bb * Ss * Dd * 2);
  // kgf/vgf first: kgf doubles as split-K bf16 buffer B (dead by Wo/FF2)
  size_t o_kgf  = alloc((size_t)Bb * Hh * Ss * 64 * 2);
  size_t o_vgf  = alloc((size_t)Bb * Hh * Ss * 64 * 2);
  size_t o_accB = o_kgf;  // bf16 half-B: 8192*768*2 bytes fits in kgf alone
  size_t o_accA = o_vgf;  // bf16 half-A: same size, vgf also dead by Wo/FF2
  size_t o_qpk  = alloc((size_t)Bb * Hh * Ss * 64 * 2);
  size_t o_kpk  = alloc((size_t)Bb * Hh * SPAD * 64 * 2);
  size_t o_vtpk = alloc((size_t)Bb * Hh * 64 * SPAD * 2);
  size_t o_kg   = alloc((size_t)Bb * Hh * 64 * 64 * 2);
  size_t o_vgt  = alloc((size_t)Bb * Hh * 64 * 64 * 2);
  size_t o_xg   = alloc((size_t)128 * Dd * 2);
  size_t o_qg   = alloc((size_t)128 * Dd * 2);
  size_t o_part = alloc((size_t)Bb * Hh * 3 * NCH * PARTF * 4);
  size_t o_f1b  = o_qpk;  // FFN hidden aliases the (dead-by-then) attention buffers
  {
    size_t f1b_bytes = (size_t)Bb * Ss * 4 * Dd * 2;
    if (off - o_qpk < f1b_bytes) off = o_qpk + ((f1b_bytes + 255) & ~(size_t)255);
  }
  size_t o_ctx = alloc((size_t)Bb * Ss * Dd * 2);
  if (ws_size < off) return;  // workspace too small -> fail visibly

  u16* Wb = (u16*)(ws + o_w);
  int* gposp = (int*)(ws + o_gpos);
  u16* xb = (u16*)(ws + o_xb);
  u16* accA = (u16*)(ws + o_accA);
  u16* accB = (u16*)(ws + o_accB);

  // setup: cnt=0, K/V pads=0 (3.3MB, pads only need to be finite), bias concat
  setup_kernel<<<512, 256, 0, stream>>>((int*)(ws + o_cnt), (u16*)(ws + o_kpk),
      (u16*)(ws + o_vtpk), bqkv, bqkvg, (float*)(ws + o_bias));

  sep_find_kernel<<<(Bb * Ss + 255) / 256, 256, 0, stream>>>(ids, (int*)(ws + o_cnt), (int*)(ws + o_list));
  sep_sort_kernel<<<Bb, 64, 0, stream>>>((int*)(ws + o_cnt), (int*)(ws + o_list), gposp);

  // weight conversions (batched over z); Wb layout [q,k,v,gk,gv,gq,wo,ff1,ff2]
  wconv_kernel<<<dim3(24, 24, 6), 256, 0, stream>>>(Wqkv,       Wb,          Dd, Dd, 3, 3, (long)DD, (long)WL);
  wconv_kernel<<<dim3(24, 24, 2), 256, 0, stream>>>(Wqkvg + DD,     Wb + 3 * DD, Dd, Dd, 1, 3, 0L, (long)WL);  // gk
  wconv_kernel<<<dim3(24, 24, 2), 256, 0, stream>>>(Wqkvg + 2 * DD, Wb + 4 * DD, Dd, Dd, 1, 3, 0L, (long)WL);  // gv
  wconv_kernel<<<dim3(24, 24, 2), 256, 0, stream>>>(Wqkvg,          Wb + 5 * DD, Dd, Dd, 1, 3, 0L, (long)WL);  // gq
  wconv_kernel<<<dim3(24, 24, 2), 256, 0, stream>>>(Wo,         Wb + 6 * DD, Dd, Dd, 1, 1, 0L, (long)WL);
  wconv_kernel<<<dim3(96, 24, 2), 256, 0, stream>>>(Wff1,       Wb + 7 * DD, Dd, 4 * Dd, 1, 1, 0L, (long)WL);
  wconv_kernel<<<dim3(24, 96, 2), 256, 0, stream>>>(Wff2,       Wb + 7 * DD + DF, 4 * Dd, Dd, 1, 1, 0L, (long)WL);

  embed_ln_kernel<<<Bb * Ss, 256, 0, stream>>>(ids, we, pe, te, embln, xb);

  for (int l = 0; l < Ll; ++l) {
    size_t wb = (size_t)l * WL;
    // fused QKV + global K/V projection (N=3840, 5 sections); grid 1920 %8==0
    gemm2_kernel<2, true><<<dim3(30, 64), 256, 0, stream>>>(xb, Wb + wb, (float*)(ws + o_bias) + (size_t)l * 3840,
        (u16*)(ws + o_qpk), (u16*)(ws + o_kpk), (u16*)(ws + o_vtpk),
        (u16*)(ws + o_kgf), (u16*)(ws + o_vgf), 3840, Dd, Dd, 0.125f);
    gather_kernel<<<Bb * Hh + Bb * Gg, 256, 0, stream>>>((u16*)(ws + o_kpk), (u16*)(ws + o_vtpk), xb, gposp,
        (u16*)(ws + o_kg), (u16*)(ws + o_vgt), (u16*)(ws + o_xg));
    // global q projection (M=128 padded rows); 6 blocks -> no XCD swizzle
    gemm2_kernel<4, false><<<dim3(6, 1), 256, 0, stream>>>((u16*)(ws + o_xg), Wb + wb + 5 * DD, bqkvg + (size_t)l * 3 * Dd,
        (u16*)(ws + o_qg), nullptr, nullptr, nullptr, nullptr, Dd, Dd, Dd, 0.125f);
    // attention
    attn_local_kernel<<<LOCAL_NB, 128, 0, stream>>>((u16*)(ws + o_qpk), (u16*)(ws + o_kpk), (u16*)(ws + o_vtpk), (u16*)(ws + o_kg), (u16*)(ws + o_vgt), amask, (u16*)(ws + o_ctx));
    attn_globalq_kernel<<<Bb * Hh * NCH, 192, 0, stream>>>((u16*)(ws + o_qg), (u16*)(ws + o_kgf), (u16*)(ws + o_vgf), amask, (float*)(ws + o_part));
    attn_gmerge_kernel<<<Bb * Hh, 256, 0, stream>>>((float*)(ws + o_part), gposp, (u16*)(ws + o_ctx));
    // output projection (split-K x2, both halves bf16) + LN  [kgf/vgf dead]
    gemm2_kernel<0, true><<<dim3(6, 64, 2), 256, 0, stream>>>((u16*)(ws + o_ctx), Wb + wb + 6 * DD, bo + (size_t)l * Dd,
        accA, accB, nullptr, nullptr, nullptr, Dd, Dd, Dd / 2, 1.0f);
    add_ln3_kernel<<<Bb * Ss, 256, 0, stream>>>(xb, accA, accB, ln1 + (size_t)l * 2 * Dd);
    // FFN
    gemm2_kernel<1, true><<<dim3(24, 64), 256, 0, stream>>>(xb, Wb + wb + 7 * DD, bff1 + (size_t)l * 4 * Dd,
        (u16*)(ws + o_f1b), nullptr, nullptr, nullptr, nullptr, 4 * Dd, Dd, Dd, 1.0f);
    gemm2_kernel<0, true><<<dim3(6, 64, 2), 256, 0, stream>>>((u16*)(ws + o_f1b), Wb + wb + 7 * DD + DF, bff2 + (size_t)l * Dd,
        accA, accB, nullptr, nullptr, nullptr, Dd, 4 * Dd, 2 * Dd, 1.0f);
    add_ln3_kernel<<<Bb * Ss, 256, 0, stream>>>(xb, accA, accB, ln2 + (size_t)l * 2 * Dd);
  }

  cls_kernel<<<Bb * NSEPn, 64, 0, stream>>>(xb, clsW, clsb, gposp, out);
}

// Round 16
// 715.644 us; speedup vs baseline: 1.0202x; 1.0202x over previous
//
#include <hip/hip_runtime.h>

// ---------------------------------------------------------------------------
// Longformer (2-layer) forward, MI355X.
// R15: revert to R13 (best verified: 715us). R14's 32x32 MFMA switch created
//      a periodic-row bank conflict (5.9M) and net-regressed; 16x16x32 GEMM
//      with T2 swizzle (0 conflicts) restored.
// ---------------------------------------------------------------------------

#define Bb 2
#define Ss 4096
#define Dd 768
#define Hh 12
#define Gg 33
#define NSEPn 32
#define Ll 2
#define SPAD 4640   // S + 544 (PADL=256 left, 288 right)
#define PADL 256
#define NCLSn 5
#define NCH 16      // key chunks for global-q attention (256 keys each)
#define PARTF 1056  // floats per (bh,qt,chunk) partial: 16*64 o + 16 m + 16 l
#define PSTR 72     // Plds row stride in u16 (144B: 16B-aligned, bank-spread)

typedef unsigned short u16;
typedef __attribute__((ext_vector_type(8))) short bv8;   // 8 x bf16
typedef __attribute__((ext_vector_type(4))) short sv4;   // 4 x bf16
typedef __attribute__((ext_vector_type(4))) float f32x4;

__device__ __forceinline__ float bf2f(u16 u) {
  unsigned v = ((unsigned)u) << 16;
  return __builtin_bit_cast(float, v);
}
__device__ __forceinline__ u16 f2bf(float f) {
  unsigned u = __builtin_bit_cast(unsigned, f);
  u += 0x7fffu + ((u >> 16) & 1u);
  return (u16)(u >> 16);
}
__device__ __forceinline__ void glds16(const void* g, void* l) {
  __builtin_amdgcn_global_load_lds(
      (const __attribute__((address_space(1))) void*)g,
      (__attribute__((address_space(3))) void*)l, 16, 0, 0);
}

// ---------------- setup: cnt=0, K/V pad rows = 0, bias concat ---------------
__global__ __launch_bounds__(256)
void setup_kernel(int* __restrict__ cnt, u16* __restrict__ kpk,
                  u16* __restrict__ vtpk, const float* __restrict__ bqkv,
                  const float* __restrict__ bqkvg, float* __restrict__ biasc) {
  int tid = blockIdx.x * 256 + threadIdx.x;
  if (tid < Bb) cnt[tid] = 0;
  if (tid < Ll * 3840) {
    int l = tid / 3840, c = tid - l * 3840;
    float v = (c < 2304) ? bqkv[l * 2304 + c]
                         : bqkvg[(l * 3 + 1) * Dd + (c - 2304)];
    biasc[tid] = v;
  }
  const int PADW = SPAD - Ss;                 // 544 pad rows per bh
  const int total = Bb * Hh * PADW * 64;      // 835584 elems per buffer
  for (int i = tid; i < total; i += gridDim.x * 256) {
    int bh = i / (PADW * 64);
    int rem = i - bh * (PADW * 64);
    int prow = rem >> 6, d = rem & 63;
    int row = (prow < PADL) ? prow : (Ss + prow);  // [0,PADL) U [PADL+Ss,SPAD)
    kpk[((size_t)bh * SPAD + row) * 64 + d] = 0;
    vtpk[((size_t)bh * 64 + d) * SPAD + row] = 0;
  }
}

// ---------------- sep finding --------------------------------------------
__global__ void sep_find_kernel(const int* __restrict__ ids, int* __restrict__ cnt,
                                int* __restrict__ list) {
  int i = blockIdx.x * 256 + threadIdx.x;
  if (i >= Bb * Ss) return;
  int b = i >> 12;
  if (ids[i] == 2) {
    int idx = atomicAdd(&cnt[b], 1);
    if (idx < 64) list[b * 64 + idx] = i & (Ss - 1);
  }
}

__global__ void sep_sort_kernel(const int* __restrict__ cnt, const int* __restrict__ list,
                                int* __restrict__ gpos) {
  int b = blockIdx.x;
  int t = threadIdx.x;
  int n = cnt[b]; if (n > 64) n = 64;
  if (t < Gg) gpos[b * Gg + t] = (t == 0) ? 0 : (Ss - 1);
  __syncthreads();
  if (t < n) {
    int v = list[b * 64 + t];
    int rank = 0;
    for (int j = 0; j < n; ++j) rank += (list[b * 64 + j] < v) ? 1 : 0;
    if (rank < NSEPn) gpos[b * Gg + 1 + rank] = v;
  }
}

// ------- weight fp32 (K,N) -> bf16 (N,K), batched; src slice (z/grp)*sstr+z%grp
__global__ __launch_bounds__(256)
void wconv_kernel(const float* __restrict__ src0, u16* __restrict__ dst0,
                  int K, int N, int grp, int sstr, long unit, long WLs) {
  __shared__ float t[32][33];
  int z = blockIdx.z;
  const float* src = src0 + (size_t)((z / grp) * sstr + (z % grp)) * K * N;
  u16* dst = dst0 + (size_t)(z / grp) * WLs + (size_t)(z % grp) * unit;
  int n0 = blockIdx.x * 32, k0 = blockIdx.y * 32;
  int tx = threadIdx.x & 31, ty = threadIdx.x >> 5;  // ty 0..7
  #pragma unroll
  for (int i = 0; i < 4; ++i)
    t[ty + i * 8][tx] = src[(size_t)(k0 + ty + i * 8) * N + n0 + tx];
  __syncthreads();
  #pragma unroll
  for (int i = 0; i < 4; ++i)
    dst[(size_t)(n0 + ty + i * 8) * K + k0 + tx] = f2bf(t[tx][ty + i * 8]);
}

// ---------------- embedding + LN (bf16 out only) ----------------------------
__global__ __launch_bounds__(256)
void embed_ln_kernel(const int* __restrict__ ids, const float* __restrict__ we,
                     const float* __restrict__ pe, const float* __restrict__ te,
                     const float* __restrict__ lnp, u16* __restrict__ xb) {
  int row = blockIdx.x;
  int s = row & (Ss - 1);
  int id = ids[row];
  int tid = threadIdx.x;
  float v[3]; float sm = 0.f, s2 = 0.f;
  #pragma unroll
  for (int i = 0; i < 3; ++i) {
    int c = tid + i * 256;
    float t = we[(size_t)id * Dd + c] + pe[(size_t)(s + 2) * Dd + c] + te[c];
    v[i] = t; sm += t; s2 += t * t;
  }
  __shared__ float r1[256], r2[256];
  r1[tid] = sm; r2[tid] = s2; __syncthreads();
  for (int o = 128; o; o >>= 1) {
    if (tid < o) { r1[tid] += r1[tid + o]; r2[tid] += r2[tid + o]; }
    __syncthreads();
  }
  float mean = r1[0] * (1.f / 768.f);
  float var  = r2[0] * (1.f / 768.f) - mean * mean;
  float rs = rsqrtf(var + 1e-5f);
  #pragma unroll
  for (int i = 0; i < 3; ++i) {
    int c = tid + i * 256;
    float o = (v[i] - mean) * rs * lnp[c] + lnp[Dd + c];
    xb[(size_t)row * Dd + c] = f2bf(o);
  }
}

// ------ residual (in-place bf16 carrier + 2 bf16 halves) + LN ---------------
// in-place safe: all reads precede first __syncthreads; rows block-exclusive.
__global__ __launch_bounds__(256)
void add_ln3_kernel(u16* __restrict__ xio, const u16* __restrict__ y0,
                    const u16* __restrict__ y1, const float* __restrict__ lnp) {
  int row = blockIdx.x;
  int tid = threadIdx.x;
  float v[3]; float sm = 0.f, s2 = 0.f;
  #pragma unroll
  for (int i = 0; i < 3; ++i) {
    int c = tid + i * 256;
    size_t idx = (size_t)row * Dd + c;
    float t = bf2f(xio[idx]) + bf2f(y0[idx]) + bf2f(y1[idx]);
    v[i] = t; sm += t; s2 += t * t;
  }
  __shared__ float r1[256], r2[256];
  r1[tid] = sm; r2[tid] = s2; __syncthreads();
  for (int o = 128; o; o >>= 1) {
    if (tid < o) { r1[tid] += r1[tid + o]; r2[tid] += r2[tid + o]; }
    __syncthreads();
  }
  float mean = r1[0] * (1.f / 768.f);
  float var  = r2[0] * (1.f / 768.f) - mean * mean;
  float rs = rsqrtf(var + 1e-5f);
  #pragma unroll
  for (int i = 0; i < 3; ++i) {
    int c = tid + i * 256;
    float o = (v[i] - mean) * rs * lnp[c] + lnp[Dd + c];
    xio[(size_t)row * Dd + c] = f2bf(o);
  }
}

// ---------------- GEMM2: 128x128 2-buffer + T2 LDS swizzle + T1 XCD swizzle -
// MODE 0: split-K: z==0 -> bf16 o0 (+bias); z==1 -> bf16 o1 (no bias)
// MODE 1: bf16 [M][N], exact gelu
// MODE 2: fused QKV+gKV: N=3840; secs: q pk / k pad / v^T pad / gk pk / gv^T
// MODE 4: bf16 [M][N] * scale
template <int MODE, bool XSWZ>
__global__ __launch_bounds__(256)
void gemm2_kernel(const u16* __restrict__ A, const u16* __restrict__ Bt,
                  const float* __restrict__ bias,
                  u16* __restrict__ o0, u16* __restrict__ o1, u16* __restrict__ o2,
                  u16* __restrict__ o3, u16* __restrict__ o4,
                  int N, int Ks, int Kl, float scale) {
  __shared__ u16 la[2][128 * 32], lb[2][128 * 32];
  int tid = threadIdx.x;
  int wave = tid >> 6, lane = tid & 63;
  int wr = wave >> 1, wc = wave & 1;
  int lg = lane >> 4, lc = lane & 15;
  // T1: XCD-aware bijective remap of the x-y plane (requires NB % 8 == 0)
  int bx = blockIdx.x, by = blockIdx.y;
  if (XSWZ) {
    int gx = gridDim.x;
    int nlin = bx + gx * by;
    int NB = gx * gridDim.y;
    nlin = (nlin & 7) * (NB >> 3) + (nlin >> 3);
    bx = nlin % gx;
    by = nlin / gx;
  }
  int row0 = by * 128, col0 = bx * 128;
  int koff = blockIdx.z * Kl;

  // T2 swizzle: linear LDS dest; lane fetches logical granule (l&3)^((l>>3)&3)
  int sgr = (lane & 3) ^ ((lane >> 3) & 3);
  const u16* Ag = A + (size_t)(row0 + wave * 32 + (lane >> 2)) * Ks + sgr * 8 + koff;
  const u16* Bg = Bt + (size_t)(col0 + wave * 32 + (lane >> 2)) * Ks + sgr * 8 + koff;
  int wofs = wave * 1024;
  int gph = (lg ^ ((lc >> 1) & 3)) * 8;   // swizzled read granule offset (u16)

  f32x4 acc[4][4];
  #pragma unroll
  for (int m = 0; m < 4; ++m)
    #pragma unroll
    for (int n = 0; n < 4; ++n) acc[m][n] = (f32x4){0.f, 0.f, 0.f, 0.f};

  glds16(Ag, la[0] + wofs);
  glds16(Ag + (size_t)16 * Ks, la[0] + wofs + 512);
  glds16(Bg, lb[0] + wofs);
  glds16(Bg + (size_t)16 * Ks, lb[0] + wofs + 512);
  __syncthreads();

  int nk = Kl >> 5;
  for (int t = 0; t < nk; ++t) {
    int cur = t & 1;
    if (t + 1 < nk) {
      int k1 = (t + 1) << 5;
      glds16(Ag + k1, la[cur ^ 1] + wofs);
      glds16(Ag + (size_t)16 * Ks + k1, la[cur ^ 1] + wofs + 512);
      glds16(Bg + k1, lb[cur ^ 1] + wofs);
      glds16(Bg + (size_t)16 * Ks + k1, lb[cur ^ 1] + wofs + 512);
    }
    bv8 af[4], bf_[4];
    #pragma unroll
    for (int m = 0; m < 4; ++m)
      af[m] = *reinterpret_cast<const bv8*>(la[cur] + (wr * 64 + m * 16 + lc) * 32 + gph);
    #pragma unroll
    for (int n = 0; n < 4; ++n)
      bf_[n] = *reinterpret_cast<const bv8*>(lb[cur] + (wc * 64 + n * 16 + lc) * 32 + gph);
    __builtin_amdgcn_s_setprio(1);
    #pragma unroll
    for (int m = 0; m < 4; ++m)
      #pragma unroll
      for (int n = 0; n < 4; ++n)
        acc[m][n] = __builtin_amdgcn_mfma_f32_16x16x32_bf16(af[m], bf_[n], acc[m][n], 0, 0, 0);
    __builtin_amdgcn_s_setprio(0);
    __syncthreads();
  }

  #pragma unroll
  for (int m = 0; m < 4; ++m) {
    int grow0 = row0 + wr * 64 + m * 16 + lg * 4;
    #pragma unroll
    for (int n = 0; n < 4; ++n) {
      int gcol = col0 + wc * 64 + n * 16 + lc;
      float bvl = bias[gcol];
      if (MODE == 0) {
        u16* od = blockIdx.z ? o1 : o0;
        float badd = blockIdx.z ? 0.f : bvl;
        #pragma unroll
        for (int r = 0; r < 4; ++r)
          od[(size_t)(grow0 + r) * N + gcol] = f2bf(acc[m][n][r] + badd);
      } else if (MODE == 1) {
        #pragma unroll
        for (int r = 0; r < 4; ++r) {
          float v = acc[m][n][r] + bvl;
          v = 0.5f * v * (1.0f + erff(v * 0.70710678118654752f));
          o0[(size_t)(grow0 + r) * N + gcol] = f2bf(v);
        }
      } else if (MODE == 4) {
        #pragma unroll
        for (int r = 0; r < 4; ++r)
          o0[(size_t)(grow0 + r) * N + gcol] = f2bf((acc[m][n][r] + bvl) * scale);
      } else if (MODE == 2) {
        int sec = (col0 >> 7) / 6;        // 0..4, block-uniform
        int colr = gcol - sec * 768;
        int hh = colr >> 6, d = colr & 63;
        int bb = grow0 >> 12, s = grow0 & (Ss - 1);
        size_t bhh = (size_t)(bb * Hh + hh);
        if (sec == 0) {
          #pragma unroll
          for (int r = 0; r < 4; ++r)
            o0[(bhh * Ss + s + r) * 64 + d] = f2bf((acc[m][n][r] + bvl) * scale);
        } else if (sec == 1) {
          #pragma unroll
          for (int r = 0; r < 4; ++r)
            o1[(bhh * SPAD + PADL + s + r) * 64 + d] = f2bf(acc[m][n][r] + bvl);
        } else if (sec == 2) {
          sv4 pk;
          #pragma unroll
          for (int r = 0; r < 4; ++r) pk[r] = (short)f2bf(acc[m][n][r] + bvl);
          *reinterpret_cast<sv4*>(o2 + (bhh * 64 + d) * SPAD + PADL + s) = pk;
        } else if (sec == 3) {
          #pragma unroll
          for (int r = 0; r < 4; ++r)
            o3[(bhh * Ss + s + r) * 64 + d] = f2bf(acc[m][n][r] + bvl);
        } else {
          sv4 pk;
          #pragma unroll
          for (int r = 0; r < 4; ++r) pk[r] = (short)f2bf(acc[m][n][r] + bvl);
          *reinterpret_cast<sv4*>(o4 + (bhh * 64 + d) * Ss + s) = pk;
        }
      }
    }
  }
}

// ---------------- gathers (merged: glob K/V + xg) ---------------------------
__global__ __launch_bounds__(256)
void gather_kernel(const u16* __restrict__ kpk, const u16* __restrict__ vtpk,
                   const u16* __restrict__ xb, const int* __restrict__ gpos,
                   u16* __restrict__ kg, u16* __restrict__ vgt,
                   u16* __restrict__ xg) {
  int blk = blockIdx.x;
  int tid = threadIdx.x;
  if (blk < Bb * Hh) {
    int bh = blk;
    int b = bh / Hh;
    for (int idx = tid; idx < 64 * 64; idx += 256) {
      int g = idx >> 6, d = idx & 63;
      u16 kv = 0, vv = 0;
      if (g < Gg) {
        int p = gpos[b * Gg + g];
        kv = kpk[((size_t)bh * SPAD + PADL + p) * 64 + d];
        vv = vtpk[((size_t)bh * 64 + d) * SPAD + PADL + p];
      }
      kg[(size_t)bh * 4096 + idx] = kv;
      vgt[((size_t)bh * 64 + d) * 64 + g] = vv;
    }
  } else {
    int rg = blk - Bb * Hh;   // b*G+g
    int b = rg / Gg;
    int p = gpos[rg];
    for (int c = tid; c < Dd; c += 256)
      xg[(size_t)rg * Dd + c] = xb[((size_t)b * Ss + p) * Dd + c];
  }
}

// ---------------- local (sliding window + global-key) attention -------------
// 2 waves/block, 2 q-tiles/wave (64 queries/block). Swapped QK^T, ballot mask,
// defer-max (THR=8). Per-step scalar overhead amortized over 32 queries/wave.
#define LOCAL_NB (Bb * Hh * (Ss / 64))   // 1536 blocks, %8 == 0
__global__ __launch_bounds__(128)
void attn_local_kernel(const u16* __restrict__ qpk, const u16* __restrict__ kpk,
                       const u16* __restrict__ vtpk, const u16* __restrict__ kg,
                       const u16* __restrict__ vgt, const int* __restrict__ amask,
                       u16* __restrict__ ctx) {
  __shared__ u16 Plds[4][16 * PSTR];
  int bid = blockIdx.x;
  int swz = (bid & 7) * (LOCAL_NB / 8) + (bid >> 3);
  int qb = swz & 63;
  int bh = swz >> 6;
  int b = bh / Hh;
  int h = bh - b * Hh;
  int wv = threadIdx.x >> 6;       // 0..1
  int q0 = qb * 64;                // block window base
  int qA = q0 + wv * 32;           // tile A rows qA..qA+15; tile B +16
  int lane = threadIdx.x & 63;
  int lg = lane >> 4, lc = lane & 15;
  int lg4 = lg * 4;
  int qa = qA + lc, qbq = qA + 16 + lc;   // this lane's queries (A, B)

  const u16* qrowA = qpk + ((size_t)bh * Ss + qA + lc) * 64;
  bv8 aqA0 = *reinterpret_cast<const bv8*>(qrowA + lg * 8);
  bv8 aqA1 = *reinterpret_cast<const bv8*>(qrowA + 32 + lg * 8);
  const u16* qrowB = qrowA + 16 * 64;
  bv8 aqB0 = *reinterpret_cast<const bv8*>(qrowB + lg * 8);
  bv8 aqB1 = *reinterpret_cast<const bv8*>(qrowB + 32 + lg * 8);

  f32x4 oA[4], oB[4];
  #pragma unroll
  for (int i = 0; i < 4; ++i) { oA[i] = (f32x4){0.f,0.f,0.f,0.f}; oB[i] = (f32x4){0.f,0.f,0.f,0.f}; }
  float mrunA = -1e30f, lrunA = 0.f, mrunB = -1e30f, lrunB = 0.f;

  const u16* kgb = kg + ((size_t)bh) * 64 * 64;
  const u16* vgb = vgt + ((size_t)bh) * 64 * 64;
  const u16* kb = kpk + ((size_t)bh) * SPAD * 64;
  const u16* vb = vtpk + ((size_t)bh) * 64 * SPAD;
  const int* amb = amask + b * Ss;
  u16* PA = &Plds[wv * 2][0];
  u16* PB = &Plds[wv * 2 + 1][0];

  // preload K frags for step 0 (global keys)
  bv8 kc[8];
  #pragma unroll
  for (int j = 0; j < 4; ++j) {
    const u16* kr = kgb + (size_t)(j * 16 + lc) * 64;
    kc[2 * j]     = *reinterpret_cast<const bv8*>(kr + lg * 8);
    kc[2 * j + 1] = *reinterpret_cast<const bv8*>(kr + 32 + lg * 8);
  }
  // prefetch amask word for step 1
  int amvN;
  { int ni = min(max(q0 - 256 + lane, 0), Ss - 1); amvN = amb[ni]; }

  for (int step = 0; step < 10; ++step) {
    bool isg = (step == 0);
    int ks = isg ? 0 : (q0 - 256 + (step - 1) * 64);
    int amvC = amvN;
    if (step < 9) { int ni = min(max(q0 - 256 + step * 64 + lane, 0), Ss - 1); amvN = amb[ni]; }

    // V loads (shared by both tiles)
    bv8 vf0[4], vf1[4];
    #pragma unroll
    for (int nt = 0; nt < 4; ++nt) {
      const u16* vr = isg ? (vgb + (size_t)(nt * 16 + lc) * 64)
                          : (vb + (size_t)(nt * 16 + lc) * SPAD + PADL + ks);
      vf0[nt] = *reinterpret_cast<const bv8*>(vr + lg * 8);
      vf1[nt] = *reinterpret_cast<const bv8*>(vr + 32 + lg * 8);
    }
    // key-validity mask
    unsigned long long kmask;
    if (isg) {
      kmask = (1ull << Gg) - 1;
    } else {
      int kidx = ks + lane;
      kmask = __ballot((kidx >= 0) && (kidx < Ss) && (amvC > 0));
    }
    // QK^T swapped: scX[j] = scores for keys ks+j*16+lg4..+3, query (tile, lc)
    f32x4 scA[4], scB[4];
    __builtin_amdgcn_s_setprio(1);
    #pragma unroll
    for (int j = 0; j < 4; ++j) {
      f32x4 z = (f32x4){0.f, 0.f, 0.f, 0.f};
      scA[j] = __builtin_amdgcn_mfma_f32_16x16x32_bf16(kc[2 * j], aqA0, z, 0, 0, 0);
      scA[j] = __builtin_amdgcn_mfma_f32_16x16x32_bf16(kc[2 * j + 1], aqA1, scA[j], 0, 0, 0);
      scB[j] = __builtin_amdgcn_mfma_f32_16x16x32_bf16(kc[2 * j], aqB0, z, 0, 0, 0);
      scB[j] = __builtin_amdgcn_mfma_f32_16x16x32_bf16(kc[2 * j + 1], aqB1, scB[j], 0, 0, 0);
    }
    __builtin_amdgcn_s_setprio(0);
    // reload kc IN PLACE for next step (WAR; hides under softmax+PV)
    if (step < 9) {
      int ksn = q0 - 256 + step * 64;
      #pragma unroll
      for (int j = 0; j < 4; ++j) {
        const u16* kr = kb + (size_t)(PADL + ksn + j * 16 + lc) * 64;
        kc[2 * j]     = *reinterpret_cast<const bv8*>(kr + lg * 8);
        kc[2 * j + 1] = *reinterpret_cast<const bv8*>(kr + 32 + lg * 8);
      }
    }
    // masking: steps 2..8 with full kmask are band-safe for all 64 queries
    bool fast = (!isg) && (step >= 2) && (step <= 8) && (kmask == ~0ull);
    float mlocA = -1e30f, mlocB = -1e30f;
    if (fast) {
      #pragma unroll
      for (int j = 0; j < 4; ++j)
        #pragma unroll
        for (int r = 0; r < 4; ++r) {
          mlocA = fmaxf(mlocA, scA[j][r]);
          mlocB = fmaxf(mlocB, scB[j][r]);
        }
    } else {
      #pragma unroll
      for (int j = 0; j < 4; ++j)
        #pragma unroll
        for (int r = 0; r < 4; ++r) {
          int kk = ks + j * 16 + lg4 + r;
          bool okk = (kmask >> (j * 16 + lg4 + r)) & 1;
          bool okA = okk, okB = okk;
          if (!isg) {
            okA = okA && ((unsigned)(kk - qa + 256) <= 512u);
            okB = okB && ((unsigned)(kk - qbq + 256) <= 512u);
          }
          scA[j][r] = okA ? scA[j][r] : -1e9f;
          scB[j][r] = okB ? scB[j][r] : -1e9f;
          mlocA = fmaxf(mlocA, scA[j][r]);
          mlocB = fmaxf(mlocB, scB[j][r]);
        }
    }
    mlocA = fmaxf(mlocA, __shfl_xor(mlocA, 16));
    mlocA = fmaxf(mlocA, __shfl_xor(mlocA, 32));
    mlocB = fmaxf(mlocB, __shfl_xor(mlocB, 16));
    mlocB = fmaxf(mlocB, __shfl_xor(mlocB, 32));
    // defer-max: only rescale when max grows by > 8 for some query
    if (__any(mlocA > mrunA + 8.f)) {
      float nm = fmaxf(mrunA, mlocA);
      float scal = __expf(mrunA - nm);
      mrunA = nm;
      lrunA *= scal;
      #pragma unroll
      for (int r = 0; r < 4; ++r) {
        float sr = __shfl(scal, lg4 + r);
        #pragma unroll
        for (int nt = 0; nt < 4; ++nt) oA[nt][r] *= sr;
      }
    }
    if (__any(mlocB > mrunB + 8.f)) {
      float nm = fmaxf(mrunB, mlocB);
      float scal = __expf(mrunB - nm);
      mrunB = nm;
      lrunB *= scal;
      #pragma unroll
      for (int r = 0; r < 4; ++r) {
        float sr = __shfl(scal, lg4 + r);
        #pragma unroll
        for (int nt = 0; nt < 4; ++nt) oB[nt][r] *= sr;
      }
    }
    float psumA = 0.f, psumB = 0.f;
    #pragma unroll
    for (int j = 0; j < 4; ++j) {
      sv4 pkA, pkB;
      #pragma unroll
      for (int r = 0; r < 4; ++r) {
        float pA = __expf(scA[j][r] - mrunA);
        float pB = __expf(scB[j][r] - mrunB);
        psumA += pA; psumB += pB;
        pkA[r] = (short)f2bf(pA);
        pkB[r] = (short)f2bf(pB);
      }
      *reinterpret_cast<sv4*>(PA + lc * PSTR + j * 16 + lg4) = pkA;
      *reinterpret_cast<sv4*>(PB + lc * PSTR + j * 16 + lg4) = pkB;
    }
    psumA += __shfl_xor(psumA, 16);
    psumA += __shfl_xor(psumA, 32);
    psumB += __shfl_xor(psumB, 16);
    psumB += __shfl_xor(psumB, 32);
    lrunA += psumA;
    lrunB += psumB;
    // PV (V frags shared between tiles)
    __builtin_amdgcn_s_setprio(1);
    {
      bv8 apA = *reinterpret_cast<const bv8*>(PA + lc * PSTR + lg * 8);
      bv8 apB = *reinterpret_cast<const bv8*>(PB + lc * PSTR + lg * 8);
      #pragma unroll
      for (int nt = 0; nt < 4; ++nt) {
        oA[nt] = __builtin_amdgcn_mfma_f32_16x16x32_bf16(apA, vf0[nt], oA[nt], 0, 0, 0);
        oB[nt] = __builtin_amdgcn_mfma_f32_16x16x32_bf16(apB, vf0[nt], oB[nt], 0, 0, 0);
      }
      apA = *reinterpret_cast<const bv8*>(PA + lc * PSTR + 32 + lg * 8);
      apB = *reinterpret_cast<const bv8*>(PB + lc * PSTR + 32 + lg * 8);
      #pragma unroll
      for (int nt = 0; nt < 4; ++nt) {
        oA[nt] = __builtin_amdgcn_mfma_f32_16x16x32_bf16(apA, vf1[nt], oA[nt], 0, 0, 0);
        oB[nt] = __builtin_amdgcn_mfma_f32_16x16x32_bf16(apB, vf1[nt], oB[nt], 0, 0, 0);
      }
    }
    __builtin_amdgcn_s_setprio(0);
  }
  float invA = 1.0f / lrunA, invB = 1.0f / lrunB;
  #pragma unroll
  for (int r = 0; r < 4; ++r) {
    float invrA = __shfl(invA, lg4 + r);
    float invrB = __shfl(invB, lg4 + r);
    size_t rowA = ((size_t)b * Ss + qA + lg4 + r) * Dd + h * 64;
    size_t rowB = rowA + (size_t)16 * Dd;
    #pragma unroll
    for (int nt = 0; nt < 4; ++nt) {
      ctx[rowA + nt * 16 + lc] = f2bf(oA[nt][r] * invrA);
      ctx[rowB + nt * 16 + lc] = f2bf(oB[nt][r] * invrB);
    }
  }
}

// ---------------- global-query attention: lane-local flash MFMA -------------
__global__ __launch_bounds__(192)
void attn_globalq_kernel(const u16* __restrict__ qgb, const u16* __restrict__ kgf,
                         const u16* __restrict__ vgt, const int* __restrict__ amask,
                         float* __restrict__ part) {
  __shared__ u16 Plds[3][16 * PSTR];
  int blk = blockIdx.x;
  int ch = blk & (NCH - 1);
  int bh = blk / NCH;
  int b = bh / Hh, h = bh - b * Hh;
  int wv = threadIdx.x >> 6;  // q-tile 0..2
  int lane = threadIdx.x & 63;
  int lg = lane >> 4, lc = lane & 15;
  int lg4 = lg * 4;

  int qrow = wv * 16 + lc;
  bv8 aq0 = (bv8)0, aq1 = (bv8)0;
  if (qrow < Gg) {
    const u16* qr = qgb + (size_t)(b * Gg + qrow) * Dd + h * 64;
    aq0 = *reinterpret_cast<const bv8*>(qr + lg * 8);
    aq1 = *reinterpret_cast<const bv8*>(qr + 32 + lg * 8);
  }

  f32x4 o[4];
  #pragma unroll
  for (int i = 0; i < 4; ++i) o[i] = (f32x4){0.f, 0.f, 0.f, 0.f};
  float mrun = -1e30f, lrun = 0.f;

  const u16* kb = kgf + ((size_t)bh) * Ss * 64;
  const u16* vb = vgt + ((size_t)bh) * 64 * Ss;
  const int* amb = amask + b * Ss;
  int ks0 = ch * (Ss / NCH);
  u16* P = &Plds[wv][0];

  // preload K frags for step 0
  bv8 kc[8];
  #pragma unroll
  for (int j = 0; j < 4; ++j) {
    const u16* kr = kb + (size_t)(ks0 + j * 16 + lc) * 64;
    kc[2 * j]     = *reinterpret_cast<const bv8*>(kr + lg * 8);
    kc[2 * j + 1] = *reinterpret_cast<const bv8*>(kr + 32 + lg * 8);
  }

  for (int st = 0; st < 4; ++st) {
    int ks = ks0 + st * 64;
    // V loads
    bv8 vf0[4], vf1[4];
    #pragma unroll
    for (int nt = 0; nt < 4; ++nt) {
      const u16* vr = vb + (size_t)(nt * 16 + lc) * Ss + ks;
      vf0[nt] = *reinterpret_cast<const bv8*>(vr + lg * 8);
      vf1[nt] = *reinterpret_cast<const bv8*>(vr + 32 + lg * 8);
    }
    unsigned long long kmask = __ballot(amb[ks + lane] > 0);
    // QK^T swapped
    f32x4 sc[4];
    __builtin_amdgcn_s_setprio(1);
    #pragma unroll
    for (int j = 0; j < 4; ++j) {
      f32x4 z = (f32x4){0.f, 0.f, 0.f, 0.f};
      sc[j] = __builtin_amdgcn_mfma_f32_16x16x32_bf16(kc[2 * j], aq0, z, 0, 0, 0);
      sc[j] = __builtin_amdgcn_mfma_f32_16x16x32_bf16(kc[2 * j + 1], aq1, sc[j], 0, 0, 0);
    }
    __builtin_amdgcn_s_setprio(0);
    // reload kc for next step
    if (st < 3) {
      int ksn = ks0 + (st + 1) * 64;
      #pragma unroll
      for (int j = 0; j < 4; ++j) {
        const u16* kr = kb + (size_t)(ksn + j * 16 + lc) * 64;
        kc[2 * j]     = *reinterpret_cast<const bv8*>(kr + lg * 8);
        kc[2 * j + 1] = *reinterpret_cast<const bv8*>(kr + 32 + lg * 8);
      }
    }
    float mloc = -1e30f;
    if (kmask == ~0ull) {
      #pragma unroll
      for (int j = 0; j < 4; ++j)
        #pragma unroll
        for (int r = 0; r < 4; ++r) mloc = fmaxf(mloc, sc[j][r]);
    } else {
      #pragma unroll
      for (int j = 0; j < 4; ++j)
        #pragma unroll
        for (int r = 0; r < 4; ++r) {
          bool ok = (kmask >> (j * 16 + lg4 + r)) & 1;
          sc[j][r] = ok ? sc[j][r] : -1e9f;
          mloc = fmaxf(mloc, sc[j][r]);
        }
    }
    mloc = fmaxf(mloc, __shfl_xor(mloc, 16));
    mloc = fmaxf(mloc, __shfl_xor(mloc, 32));
    if (__any(mloc > mrun + 8.f)) {
      float nm = fmaxf(mrun, mloc);
      float scal = __expf(mrun - nm);
      mrun = nm;
      lrun *= scal;
      #pragma unroll
      for (int r = 0; r < 4; ++r) {
        float sr = __shfl(scal, lg4 + r);
        #pragma unroll
        for (int nt = 0; nt < 4; ++nt) o[nt][r] *= sr;
      }
    }
    float psum = 0.f;
    #pragma unroll
    for (int j = 0; j < 4; ++j) {
      sv4 pk;
      #pragma unroll
      for (int r = 0; r < 4; ++r) {
        float p = __expf(sc[j][r] - mrun);
        psum += p;
        pk[r] = (short)f2bf(p);
      }
      *reinterpret_cast<sv4*>(P + lc * PSTR + j * 16 + lg4) = pk;
    }
    psum += __shfl_xor(psum, 16);
    psum += __shfl_xor(psum, 32);
    lrun += psum;
    __builtin_amdgcn_s_setprio(1);
    {
      bv8 ap = *reinterpret_cast<const bv8*>(P + lc * PSTR + lg * 8);
      #pragma unroll
      for (int nt = 0; nt < 4; ++nt)
        o[nt] = __builtin_amdgcn_mfma_f32_16x16x32_bf16(ap, vf0[nt], o[nt], 0, 0, 0);
      ap = *reinterpret_cast<const bv8*>(P + lc * PSTR + 32 + lg * 8);
      #pragma unroll
      for (int nt = 0; nt < 4; ++nt)
        o[nt] = __builtin_amdgcn_mfma_f32_16x16x32_bf16(ap, vf1[nt], o[nt], 0, 0, 0);
    }
    __builtin_amdgcn_s_setprio(0);
  }

  float* pb = part + ((size_t)(bh * 3 + wv) * NCH + ch) * PARTF;
  #pragma unroll
  for (int r = 0; r < 4; ++r) {
    int row = lg4 + r;
    #pragma unroll
    for (int nt = 0; nt < 4; ++nt)
      pb[row * 64 + nt * 16 + lc] = o[nt][r];
  }
  if (lg == 0) {
    pb[1024 + lc] = mrun;
    pb[1040 + lc] = lrun;
  }
}

// merge NCH chunk-partials and scatter into ctx rows at gpos
__global__ __launch_bounds__(256)
void attn_gmerge_kernel(const float* __restrict__ part, const int* __restrict__ gpos,
                        u16* __restrict__ ctx) {
  __shared__ float wgt[Gg][NCH];
  __shared__ float sinvl[Gg];
  int bh = blockIdx.x;
  int b = bh / Hh, h = bh - b * Hh;
  int tid = threadIdx.x;
  if (tid < Gg) {
    int qt = tid >> 4, rr = tid & 15;
    const float* pb = part + ((size_t)(bh * 3 + qt) * NCH) * PARTF;
    float mx = -1e30f;
    for (int c = 0; c < NCH; ++c) mx = fmaxf(mx, pb[c * PARTF + 1024 + rr]);
    float l = 0.f;
    for (int c = 0; c < NCH; ++c) {
      float w = __expf(pb[c * PARTF + 1024 + rr] - mx);
      wgt[tid][c] = w;
      l += w * pb[c * PARTF + 1040 + rr];
    }
    sinvl[tid] = 1.0f / l;
  }
  __syncthreads();
  for (int e = tid; e < Gg * 64; e += 256) {
    int row = e >> 6, d = e & 63;
    int qt = row >> 4, rr = row & 15;
    const float* pb = part + ((size_t)(bh * 3 + qt) * NCH) * PARTF + rr * 64 + d;
    float acc = 0.f;
    #pragma unroll
    for (int c = 0; c < NCH; ++c) acc += wgt[row][c] * pb[c * PARTF];
    int pos = gpos[b * Gg + row];
    ctx[((size_t)b * Ss + pos) * Dd + h * 64 + d] = f2bf(acc * sinvl[row]);
  }
}

// ---------------- classifier (bf16 x) ---------------------------------------
__global__ __launch_bounds__(64)
void cls_kernel(const u16* __restrict__ x, const float* __restrict__ W,
                const float* __restrict__ bias, const int* __restrict__ gpos,
                float* __restrict__ out) {
  int r = blockIdx.x;  // b*32 + i
  int b = r >> 5, i = r & 31;
  int pos = gpos[b * Gg + 1 + i];
  int lane = threadIdx.x;
  const u16* xr = x + ((size_t)b * Ss + pos) * Dd;
  float acc[NCLSn] = {0.f, 0.f, 0.f, 0.f, 0.f};
  for (int k = lane; k < Dd; k += 64) {
    float xv = bf2f(xr[k]);
    #pragma unroll
    for (int c = 0; c < NCLSn; ++c) acc[c] += xv * W[c * Dd + k];
  }
  #pragma unroll
  for (int c = 0; c < NCLSn; ++c) {
    #pragma unroll
    for (int off = 1; off < 64; off <<= 1) acc[c] += __shfl_xor(acc[c], off);
  }
  if (lane == 0) {
    #pragma unroll
    for (int c = 0; c < NCLSn; ++c) out[r * NCLSn + c] = acc[c] + bias[c];
  }
}

// ---------------------------------------------------------------------------
extern "C" void kernel_launch(void* const* d_in, const int* in_sizes, int n_in,
                              void* d_out, int out_size, void* d_ws, size_t ws_size,
                              hipStream_t stream) {
  const int* ids     = (const int*)d_in[0];
  const int* amask   = (const int*)d_in[1];
  const float* we    = (const float*)d_in[2];
  const float* pe    = (const float*)d_in[3];
  const float* te    = (const float*)d_in[4];
  const float* embln = (const float*)d_in[5];
  const float* Wqkv  = (const float*)d_in[6];
  const float* bqkv  = (const float*)d_in[7];
  const float* Wqkvg = (const float*)d_in[8];
  const float* bqkvg = (const float*)d_in[9];
  const float* Wo    = (const float*)d_in[10];
  const float* bo    = (const float*)d_in[11];
  const float* ln1   = (const float*)d_in[12];
  const float* Wff1  = (const float*)d_in[13];
  const float* bff1  = (const float*)d_in[14];
  const float* Wff2  = (const float*)d_in[15];
  const float* bff2  = (const float*)d_in[16];
  const float* ln2   = (const float*)d_in[17];
  const float* clsW  = (const float*)d_in[18];
  const float* clsb  = (const float*)d_in[19];
  float* out = (float*)d_out;

  char* ws = (char*)d_ws;
  size_t off = 0;
  auto alloc = [&](size_t bytes) { size_t o = off; off += (bytes + 255) & ~(size_t)255; return o; };

  const size_t DD = (size_t)Dd * Dd;        // 589824
  const size_t DF = (size_t)Dd * 4 * Dd;    // 2359296
  const size_t WL = 7 * DD + 2 * DF;        // elems per layer
  // Wb layout per layer: [q,k,v, gk,gv, gq, wo, ff1, ff2]

  size_t o_cnt  = alloc(Bb * 4);
  size_t o_list = alloc(Bb * 64 * 4);
  size_t o_gpos = alloc(Bb * Gg * 4);
  size_t o_bias = alloc((size_t)Ll * 3840 * 4);
  size_t o_w    = alloc(WL * Ll * 2);
  size_t o_xb   = alloc((size_t)Bb * Ss * Dd * 2);
  // kgf/vgf first: kgf doubles as split-K bf16 buffer B (dead by Wo/FF2)
  size_t o_kgf  = alloc((size_t)Bb * Hh * Ss * 64 * 2);
  size_t o_vgf  = alloc((size_t)Bb * Hh * Ss * 64 * 2);
  size_t o_accB = o_kgf;  // bf16 half-B: 8192*768*2 bytes fits in kgf alone
  size_t o_accA = o_vgf;  // bf16 half-A: same size, vgf also dead by Wo/FF2
  size_t o_qpk  = alloc((size_t)Bb * Hh * Ss * 64 * 2);
  size_t o_kpk  = alloc((size_t)Bb * Hh * SPAD * 64 * 2);
  size_t o_vtpk = alloc((size_t)Bb * Hh * 64 * SPAD * 2);
  size_t o_kg   = alloc((size_t)Bb * Hh * 64 * 64 * 2);
  size_t o_vgt  = alloc((size_t)Bb * Hh * 64 * 64 * 2);
  size_t o_xg   = alloc((size_t)128 * Dd * 2);
  size_t o_qg   = alloc((size_t)128 * Dd * 2);
  size_t o_part = alloc((size_t)Bb * Hh * 3 * NCH * PARTF * 4);
  size_t o_f1b  = o_qpk;  // FFN hidden aliases the (dead-by-then) attention buffers
  {
    size_t f1b_bytes = (size_t)Bb * Ss * 4 * Dd * 2;
    if (off - o_qpk < f1b_bytes) off = o_qpk + ((f1b_bytes + 255) & ~(size_t)255);
  }
  size_t o_ctx = alloc((size_t)Bb * Ss * Dd * 2);
  if (ws_size < off) return;  // workspace too small -> fail visibly

  u16* Wb = (u16*)(ws + o_w);
  int* gposp = (int*)(ws + o_gpos);
  u16* xb = (u16*)(ws + o_xb);
  u16* accA = (u16*)(ws + o_accA);
  u16* accB = (u16*)(ws + o_accB);

  // setup: cnt=0, K/V pads=0 (3.3MB, pads only need to be finite), bias concat
  setup_kernel<<<512, 256, 0, stream>>>((int*)(ws + o_cnt), (u16*)(ws + o_kpk),
      (u16*)(ws + o_vtpk), bqkv, bqkvg, (float*)(ws + o_bias));

  sep_find_kernel<<<(Bb * Ss + 255) / 256, 256, 0, stream>>>(ids, (int*)(ws + o_cnt), (int*)(ws + o_list));
  sep_sort_kernel<<<Bb, 64, 0, stream>>>((int*)(ws + o_cnt), (int*)(ws + o_list), gposp);

  // weight conversions (batched over z); Wb layout [q,k,v,gk,gv,gq,wo,ff1,ff2]
  wconv_kernel<<<dim3(24, 24, 6), 256, 0, stream>>>(Wqkv,       Wb,          Dd, Dd, 3, 3, (long)DD, (long)WL);
  wconv_kernel<<<dim3(24, 24, 2), 256, 0, stream>>>(Wqkvg + DD,     Wb + 3 * DD, Dd, Dd, 1, 3, 0L, (long)WL);  // gk
  wconv_kernel<<<dim3(24, 24, 2), 256, 0, stream>>>(Wqkvg + 2 * DD, Wb + 4 * DD, Dd, Dd, 1, 3, 0L, (long)WL);  // gv
  wconv_kernel<<<dim3(24, 24, 2), 256, 0, stream>>>(Wqkvg,          Wb + 5 * DD, Dd, Dd, 1, 3, 0L, (long)WL);  // gq
  wconv_kernel<<<dim3(24, 24, 2), 256, 0, stream>>>(Wo,         Wb + 6 * DD, Dd, Dd, 1, 1, 0L, (long)WL);
  wconv_kernel<<<dim3(96, 24, 2), 256, 0, stream>>>(Wff1,       Wb + 7 * DD, Dd, 4 * Dd, 1, 1, 0L, (long)WL);
  wconv_kernel<<<dim3(24, 96, 2), 256, 0, stream>>>(Wff2,       Wb + 7 * DD + DF, 4 * Dd, Dd, 1, 1, 0L, (long)WL);

  embed_ln_kernel<<<Bb * Ss, 256, 0, stream>>>(ids, we, pe, te, embln, xb);

  for (int l = 0; l < Ll; ++l) {
    size_t wb = (size_t)l * WL;
    // fused QKV + global K/V projection (N=3840, 5 sections); grid 1920 %8==0
    gemm2_kernel<2, true><<<dim3(30, 64), 256, 0, stream>>>(xb, Wb + wb, (float*)(ws + o_bias) + (size_t)l * 3840,
        (u16*)(ws + o_qpk), (u16*)(ws + o_kpk), (u16*)(ws + o_vtpk),
        (u16*)(ws + o_kgf), (u16*)(ws + o_vgf), 3840, Dd, Dd, 0.125f);
    gather_kernel<<<Bb * Hh + Bb * Gg, 256, 0, stream>>>((u16*)(ws + o_kpk), (u16*)(ws + o_vtpk), xb, gposp,
        (u16*)(ws + o_kg), (u16*)(ws + o_vgt), (u16*)(ws + o_xg));
    // global q projection (M=128 padded rows); 6 blocks -> no XCD swizzle
    gemm2_kernel<4, false><<<dim3(6, 1), 256, 0, stream>>>((u16*)(ws + o_xg), Wb + wb + 5 * DD, bqkvg + (size_t)l * 3 * Dd,
        (u16*)(ws + o_qg), nullptr, nullptr, nullptr, nullptr, Dd, Dd, Dd, 0.125f);
    // attention
    attn_local_kernel<<<LOCAL_NB, 128, 0, stream>>>((u16*)(ws + o_qpk), (u16*)(ws + o_kpk), (u16*)(ws + o_vtpk), (u16*)(ws + o_kg), (u16*)(ws + o_vgt), amask, (u16*)(ws + o_ctx));
    attn_globalq_kernel<<<Bb * Hh * NCH, 192, 0, stream>>>((u16*)(ws + o_qg), (u16*)(ws + o_kgf), (u16*)(ws + o_vgf), amask, (float*)(ws + o_part));
    attn_gmerge_kernel<<<Bb * Hh, 256, 0, stream>>>((float*)(ws + o_part), gposp, (u16*)(ws + o_ctx));
    // output projection (split-K x2, both halves bf16) + LN  [kgf/vgf dead]
    gemm2_kernel<0, true><<<dim3(6, 64, 2), 256, 0, stream>>>((u16*)(ws + o_ctx), Wb + wb + 6 * DD, bo + (size_t)l * Dd,
        accA, accB, nullptr, nullptr, nullptr, Dd, Dd, Dd / 2, 1.0f);
    add_ln3_kernel<<<Bb * Ss, 256, 0, stream>>>(xb, accA, accB, ln1 + (size_t)l * 2 * Dd);
    // FFN
    gemm2_kernel<1, true><<<dim3(24, 64), 256, 0, stream>>>(xb, Wb + wb + 7 * DD, bff1 + (size_t)l * 4 * Dd,
        (u16*)(ws + o_f1b), nullptr, nullptr, nullptr, nullptr, 4 * Dd, Dd, Dd, 1.0f);
    gemm2_kernel<0, true><<<dim3(6, 64, 2), 256, 0, stream>>>((u16*)(ws + o_f1b), Wb + wb + 7 * DD + DF, bff2 + (size_t)l * Dd,
        accA, accB, nullptr, nullptr, nullptr, Dd, 4 * Dd, 2 * Dd, 1.0f);
    add_ln3_kernel<<<Bb * Ss, 256, 0, stream>>>(xb, accA, accB, ln2 + (size_t)l * 2 * Dd);
  }

  cls_kernel<<<Bb * NSEPn, 64, 0, stream>>>(xb, clsW, clsb, gposp, out);
}